// Round 16
// baseline (49.556 us; speedup 1.0000x reference)
//
#include <hip/hip_runtime.h>

// LIF scan, B=65536 x L=400. Round 16: r15 + 2-chunk-deep read prefetch.
// Evidence ledger:
//   r10: 38.8us (ROWS=64, 1 wave/SIMD). r15: 38.2us (ROWS=32, 2 waves/SIMD,
//   VALUBusy 25%) -> TLP scaling weak (wave issue cost is exec-mask-blind).
//   Counters stable: FETCH 55MB, WRITE 104MB, conflicts 0.5M. Effective HBM
//   4.2 TB/s vs 6.3 copy ceiling. Reads block (vmcnt) and prefetch is 1 deep:
//   each wave's read queue is empty ~75% of its chunk period. Stores never
//   block (fill kernel: 7.1 TB/s @ 10% occupancy). Theory: read-queue duty
//   cycle is the remaining limiter.
// Single change vs r15: second prefetch buffer. Iter c issues load(c+2);
// LDS holds c, B-buffer holds c+1 -> ~20KB outstanding per wave continuously.
// Hand-unrolled 5 iters, A/B statically named (rule #20, r11 lesson).
// __launch_bounds__(64,2) caps VGPR at 256 so 2 waves/SIMD survive.
// div20 = Markstein 2-fma correctly-rounded v/20 (validated r3-r15).

#define L_LEN 400
#define TC 80
#define NC 5
#define F4C 20
#define ROWS 32
#define F4T 10               // load/store instrs per chunk = ROWS*F4C/64
#define PITCHF 96
#define BIG 0x7fffffff

typedef float f4 __attribute__((ext_vector_type(4)));

__device__ __forceinline__ float div20(float v) {
    const float c = 0.05f;
    float q = v * c;
    float r = fmaf(-20.0f, q, v);
    return fmaf(r, c, q);
}

__global__ __launch_bounds__(64, 2) void lif_kernel(const float* __restrict__ I,
                                                    float* __restrict__ spikes,
                                                    float* __restrict__ hard_lat,
                                                    float* __restrict__ soft_lat) {
    __shared__ float lds_in[ROWS * PITCHF];   // 12288 B
    __shared__ unsigned bitsb[ROWS * 3];      // 384 B
    const int j = threadIdx.x;
    const int R0 = blockIdx.x * ROWS;
    const char* Ib = (const char*)I + (size_t)R0 * 1600;
    char* Sb = (char*)spikes + (size_t)R0 * 1600;

    const int r0 = j / 20;
    const int k0 = j - r0 * 20;
    const int jx = j & 7;
    float* myrow = &lds_in[j * PITCHF];       // valid for j < ROWS

    float v = 0.0f;
    int num = 0, cnt = 0, first = BIG;

    f4 A[F4T], B[F4T];

    auto load_coal = [&](int c, f4* rg) {     // c literal at every call site
        int r = r0, k = k0;
        int off = r * 1600 + k * 16 + c * 320;
#pragma unroll
        for (int i = 0; i < F4T; ++i) {
            rg[i] = *reinterpret_cast<const f4*>(Ib + off);
            int kn = k + 4; bool cr = kn >= 20;
            k = cr ? kn - 20 : kn;
            r += cr ? 4 : 3;
            off += cr ? 6144 : 4864;
        }
    };

    auto write_lds = [&](const f4* rg) {
        int r = r0, k = k0;
#pragma unroll
        for (int i = 0; i < F4T; ++i) {
            *reinterpret_cast<f4*>(&lds_in[r * PITCHF + ((k ^ (r & 7)) << 2)]) = rg[i];
            int kn = k + 4; bool cr = kn >= 20;
            k = cr ? kn - 20 : kn;
            r += cr ? 4 : 3;
        }
    };

    auto scan = [&](int c) {                  // c literal at every call site
        if (j < ROWS) {
            unsigned b0 = 0, b1 = 0, b2 = 0;
            int numL = 0;
#pragma unroll
            for (int k = 0; k < F4C; ++k) {
                f4 x4 = *reinterpret_cast<const f4*>(&myrow[((k ^ jx) << 2)]);
#pragma unroll
                for (int m = 0; m < 4; ++m) {
                    const int tl = k * 4 + m;
                    float x = x4[m];
                    // reference association: v = v + ((-v/20) + x)
                    float d  = x - div20(v);
                    float vn = v + d;
                    bool fire = vn >= 1.0f;
                    numL = fire ? numL + tl : numL;
                    if (tl < 32)      b0 |= fire ? (1u << tl) : 0u;
                    else if (tl < 64) b1 |= fire ? (1u << (tl - 32)) : 0u;
                    else              b2 |= fire ? (1u << (tl - 64)) : 0u;
                    v = fire ? 0.0f : vn;
                }
            }
            int cntC = __builtin_popcount(b0) + __builtin_popcount(b1) +
                       __builtin_popcount(b2);
            int fl = b0 ? __builtin_ctz(b0)
                   : (b1 ? 32 + __builtin_ctz(b1)
                   : (b2 ? 64 + __builtin_ctz(b2) : -1));
            int cbase = c * TC;
            num += numL + cbase * cntC;
            cnt += cntC;
            first = min(first, fl >= 0 ? cbase + fl : BIG);
            bitsb[j * 3 + 0] = b0;
            bitsb[j * 3 + 1] = b1;
            bitsb[j * 3 + 2] = b2;
        }
        // single wave: exec reconverges; DS in-order -> expand sees bits
    };

    auto expand_store = [&](int c) {
        int r = r0, k = k0;
        int off = r * 1600 + k * 16 + c * 320;
#pragma unroll
        for (int i = 0; i < F4T; ++i) {
            unsigned w = bitsb[r * 3 + (k >> 3)];
            int sh = (k & 7) * 4;
            f4 s;
            s.x = (float)((w >> (sh + 0)) & 1u);
            s.y = (float)((w >> (sh + 1)) & 1u);
            s.z = (float)((w >> (sh + 2)) & 1u);
            s.w = (float)((w >> (sh + 3)) & 1u);
            __builtin_nontemporal_store(s, reinterpret_cast<f4*>(Sb + off));
            int kn = k + 4; bool cr = kn >= 20;
            k = cr ? kn - 20 : kn;
            r += cr ? 4 : 3;
            off += cr ? 6144 : 4864;
        }
    };

    // ---- static 2-deep pipeline (hand-unrolled; A/B named, no runtime select)
    load_coal(0, A);
    load_coal(1, B);
    write_lds(A);                       // chunk0 -> LDS; A free

    /* c=0 */ load_coal(2, A);  scan(0); expand_store(0); write_lds(B);  // B free
    /* c=1 */ load_coal(3, B);  scan(1); expand_store(1); write_lds(A);  // A free
    /* c=2 */ load_coal(4, A);  scan(2); expand_store(2); write_lds(B);
    /* c=3 */                   scan(3); expand_store(3); write_lds(A);
    /* c=4 */                   scan(4); expand_store(4);

    if (j < ROWS) {
        const int row = R0 + j;
        hard_lat[row] = (float)(first == BIG ? 0 : first);
        soft_lat[row] = (float)num / ((float)cnt + 1e-6f);
    }
}

extern "C" void kernel_launch(void* const* d_in, const int* in_sizes, int n_in,
                              void* d_out, int out_size, void* d_ws, size_t ws_size,
                              hipStream_t stream) {
    const float* I = (const float*)d_in[0];
    int B = in_sizes[0] / L_LEN;  // 65536

    float* spk = (float*)d_out;
    float* hard = spk + (size_t)B * L_LEN;
    float* soft = hard + B;

    dim3 block(64);
    dim3 grid(B / ROWS);  // 2048 blocks -> 8 blocks/CU = 2 waves/SIMD
    hipLaunchKernelGGL(lif_kernel, grid, block, 0, stream, I, spk, hard, soft);
}

// Round 17
// 45.250 us; speedup vs baseline: 1.0952x; 1.0952x over previous
//
#include <hip/hip_runtime.h>

// LIF scan, B=65536 x L=400. Round 17: r15 structure, ROWS=16 -> 4 waves/SIMD.
// Evidence ledger:
//   r10: 38.8 (ROWS=64, 1 w/SIMD) -> r15: 38.2 (ROWS=32, 2 w/SIMD, VALU 25%).
//   r16 (2-deep prefetch): 49.6us, FETCH+WRITE inflated — read||write in-flight
//     pressure degrades L2 handling (r4/r6 pathology in miniature). Reverted.
//   Fabric accounting: 209MB/38.2us = 5.47 TB/s = 87% of the 6.29 copy ceiling.
//   Residual ~5us = latency duty-cycle; TLP trend (r10->r15) still positive.
// Single change vs r15: ROWS=16, grid=4096 -> 16 blocks/CU = 4 waves/SIMD.
// Scan on lanes 0-15; loads/stores still 1KB-contiguous per instruction
// (F4T=5 per chunk). 1-deep prefetch only (r16 lesson). If >=37.5us or traffic
// inflates: TLP exhausted, declare roofline at r15.
// div20 = Markstein 2-fma correctly-rounded v/20 (validated r3-r16).

#define L_LEN 400
#define TC 80
#define NC 5
#define F4C 20
#define ROWS 16
#define F4T 5                // load/store instrs per chunk = ROWS*F4C/64
#define PITCHF 96
#define BIG 0x7fffffff

typedef float f4 __attribute__((ext_vector_type(4)));

__device__ __forceinline__ float div20(float v) {
    const float c = 0.05f;
    float q = v * c;
    float r = fmaf(-20.0f, q, v);
    return fmaf(r, c, q);
}

__global__ __launch_bounds__(64) void lif_kernel(const float* __restrict__ I,
                                                 float* __restrict__ spikes,
                                                 float* __restrict__ hard_lat,
                                                 float* __restrict__ soft_lat) {
    __shared__ float lds_in[ROWS * PITCHF];   // 6144 B
    __shared__ unsigned bitsb[ROWS * 3];      // 192 B
    const int j = threadIdx.x;
    const int R0 = blockIdx.x * ROWS;
    const char* Ib = (const char*)I + (size_t)R0 * 1600;
    char* Sb = (char*)spikes + (size_t)R0 * 1600;

    // coalesced walker: flat = i*64+j in [0, ROWS*F4C); r = flat/20, k = flat%20
    const int r0 = j / 20;
    const int k0 = j - r0 * 20;
    const int jx = j & 7;
    float* myrow = &lds_in[j * PITCHF];       // valid for j < ROWS

    f4 regs[F4T];

    auto load_coal = [&](int c, f4* rg) {
        int r = r0, k = k0;
        int off = r * 1600 + k * 16 + c * 320;
#pragma unroll
        for (int i = 0; i < F4T; ++i) {
            rg[i] = *reinterpret_cast<const f4*>(Ib + off);
            int kn = k + 4; bool cr = kn >= 20;
            k = cr ? kn - 20 : kn;
            r += cr ? 4 : 3;
            off += cr ? 6144 : 4864;
        }
    };

    auto write_lds = [&](const f4* rg) {
        int r = r0, k = k0;
#pragma unroll
        for (int i = 0; i < F4T; ++i) {
            *reinterpret_cast<f4*>(&lds_in[r * PITCHF + ((k ^ (r & 7)) << 2)]) = rg[i];
            int kn = k + 4; bool cr = kn >= 20;
            k = cr ? kn - 20 : kn;
            r += cr ? 4 : 3;
        }
    };

    load_coal(0, regs);
    write_lds(regs);

    float v = 0.0f;
    int num = 0, cnt = 0, first = BIG;

#pragma unroll 1
    for (int c = 0; c < NC; ++c) {
        if (c + 1 < NC) load_coal(c + 1, regs);   // 1-deep prefetch (r16 lesson)

        if (j < ROWS) {
            // ---- scan chunk c from LDS (swizzled b128 reads) ----
            unsigned b0 = 0, b1 = 0, b2 = 0;
            int numL = 0;
#pragma unroll
            for (int k = 0; k < F4C; ++k) {
                f4 x4 = *reinterpret_cast<const f4*>(&myrow[((k ^ jx) << 2)]);
#pragma unroll
                for (int m = 0; m < 4; ++m) {
                    const int tl = k * 4 + m;
                    float x = x4[m];
                    // reference association: v = v + ((-v/20) + x)
                    float d  = x - div20(v);
                    float vn = v + d;
                    bool fire = vn >= 1.0f;
                    numL = fire ? numL + tl : numL;
                    if (tl < 32)      b0 |= fire ? (1u << tl) : 0u;
                    else if (tl < 64) b1 |= fire ? (1u << (tl - 32)) : 0u;
                    else              b2 |= fire ? (1u << (tl - 64)) : 0u;
                    v = fire ? 0.0f : vn;
                }
            }
            int cntC = __builtin_popcount(b0) + __builtin_popcount(b1) +
                       __builtin_popcount(b2);
            int fl = b0 ? __builtin_ctz(b0)
                   : (b1 ? 32 + __builtin_ctz(b1)
                   : (b2 ? 64 + __builtin_ctz(b2) : -1));
            int cbase = c * TC;
            num += numL + cbase * cntC;
            cnt += cntC;
            first = min(first, fl >= 0 ? cbase + fl : BIG);

            bitsb[j * 3 + 0] = b0;
            bitsb[j * 3 + 1] = b1;
            bitsb[j * 3 + 2] = b2;
        }
        // single wave: exec reconverges; DS in-order -> expand sees bits

        // ---- expand: all 64 lanes, coalesced full-line nt stores ----
        {
            int r = r0, k = k0;
            int off = r * 1600 + k * 16 + c * 320;
#pragma unroll
            for (int i = 0; i < F4T; ++i) {
                unsigned w = bitsb[r * 3 + (k >> 3)];
                int sh = (k & 7) * 4;
                f4 s;
                s.x = (float)((w >> (sh + 0)) & 1u);
                s.y = (float)((w >> (sh + 1)) & 1u);
                s.z = (float)((w >> (sh + 2)) & 1u);
                s.w = (float)((w >> (sh + 3)) & 1u);
                __builtin_nontemporal_store(s, reinterpret_cast<f4*>(Sb + off));
                int kn = k + 4; bool cr = kn >= 20;
                k = cr ? kn - 20 : kn;
                r += cr ? 4 : 3;
                off += cr ? 6144 : 4864;
            }
        }

        if (c + 1 < NC) write_lds(regs);
    }

    if (j < ROWS) {
        const int row = R0 + j;
        hard_lat[row] = (float)(first == BIG ? 0 : first);
        soft_lat[row] = (float)num / ((float)cnt + 1e-6f);
    }
}

extern "C" void kernel_launch(void* const* d_in, const int* in_sizes, int n_in,
                              void* d_out, int out_size, void* d_ws, size_t ws_size,
                              hipStream_t stream) {
    const float* I = (const float*)d_in[0];
    int B = in_sizes[0] / L_LEN;  // 65536

    float* spk = (float*)d_out;
    float* hard = spk + (size_t)B * L_LEN;
    float* soft = hard + B;

    dim3 block(64);
    dim3 grid(B / ROWS);  // 4096 blocks -> 16 blocks/CU = 4 waves/SIMD
    hipLaunchKernelGGL(lif_kernel, grid, block, 0, stream, I, spk, hard, soft);
}

// Round 18
// 38.156 us; speedup vs baseline: 1.2988x; 1.1859x over previous
//
#include <hip/hip_runtime.h>

// LIF scan, B=65536 x L=400. FINAL (= round-15 best, reverting r17 probe).
// 38.2us on MI355X. Fabric: 209MB compulsory motion / 38.2us = 5.47 TB/s =
// 87% of the 6.29 TB/s demonstrated copy ceiling, under a structural
// ~2-waves/SIMD cap from the sequential-in-t scan (1 row = 1 thread).
// Measured TLP curve: 1w=38.8, 2w=38.2 (min), 4w=45.3 (issue-bound).
// Proven components:
//   - block=64 threads, ROWS=32 rows/block, grid=2048 (8 blocks/CU).
//   - coop coalesced global->reg loads (1KB contiguous per instruction),
//     1-deep prefetch (2-deep inflates L2 traffic, r16).
//   - reg->LDS at pitch 96 floats, slot swizzle (k ^ (r&7)): conflict-free
//     ds_read_b128 on the scan side.
//   - scan on lanes 0-31, bit-packed spikes (80b/chunk -> 3 u32) to LDS.
//   - expand: all 64 lanes, full-line float4 NONTEMPORAL stores (nt is
//     benign on full-line streams, -2.5us; pathological only with the
//     dedicated-store-wave structure, r4/r6/r7).
//   - div20 = Markstein 2-fma correctly-rounded v/20 (bit-exact vs IEEE
//     divide; absmax 2.0 == IEEE-div runs, threshold 7.2).
//   - single wave/block: exec-mask reconvergence + in-order DS ops -> zero
//     barriers in the whole kernel.

#define L_LEN 400
#define TC 80
#define NC 5
#define F4C 20
#define ROWS 32
#define F4T 10               // load/store instrs per chunk = ROWS*F4C/64
#define PITCHF 96
#define BIG 0x7fffffff

typedef float f4 __attribute__((ext_vector_type(4)));

__device__ __forceinline__ float div20(float v) {
    const float c = 0.05f;
    float q = v * c;
    float r = fmaf(-20.0f, q, v);
    return fmaf(r, c, q);
}

__global__ __launch_bounds__(64) void lif_kernel(const float* __restrict__ I,
                                                 float* __restrict__ spikes,
                                                 float* __restrict__ hard_lat,
                                                 float* __restrict__ soft_lat) {
    __shared__ float lds_in[ROWS * PITCHF];   // 12288 B
    __shared__ unsigned bitsb[ROWS * 3];      // 384 B
    const int j = threadIdx.x;
    const int R0 = blockIdx.x * ROWS;
    const char* Ib = (const char*)I + (size_t)R0 * 1600;
    char* Sb = (char*)spikes + (size_t)R0 * 1600;

    // coalesced walker: flat = i*64+j in [0, ROWS*F4C), r = flat/20, k = flat%20
    const int r0 = j / 20;
    const int k0 = j - r0 * 20;
    const int jx = j & 7;
    float* myrow = &lds_in[j * PITCHF];       // valid for j < ROWS

    f4 regs[F4T];

    auto load_coal = [&](int c, f4* rg) {
        int r = r0, k = k0;
        int off = r * 1600 + k * 16 + c * 320;
#pragma unroll
        for (int i = 0; i < F4T; ++i) {
            rg[i] = *reinterpret_cast<const f4*>(Ib + off);
            int kn = k + 4; bool cr = kn >= 20;
            k = cr ? kn - 20 : kn;
            r += cr ? 4 : 3;
            off += cr ? 6144 : 4864;
        }
    };

    auto write_lds = [&](const f4* rg) {
        int r = r0, k = k0;
#pragma unroll
        for (int i = 0; i < F4T; ++i) {
            *reinterpret_cast<f4*>(&lds_in[r * PITCHF + ((k ^ (r & 7)) << 2)]) = rg[i];
            int kn = k + 4; bool cr = kn >= 20;
            k = cr ? kn - 20 : kn;
            r += cr ? 4 : 3;
        }
    };

    load_coal(0, regs);
    write_lds(regs);

    float v = 0.0f;
    int num = 0, cnt = 0, first = BIG;

#pragma unroll 1
    for (int c = 0; c < NC; ++c) {
        if (c + 1 < NC) load_coal(c + 1, regs);   // prefetch under the scan

        if (j < ROWS) {
            // ---- scan chunk c from LDS (swizzled b128 reads) ----
            unsigned b0 = 0, b1 = 0, b2 = 0;
            int numL = 0;
#pragma unroll
            for (int k = 0; k < F4C; ++k) {
                f4 x4 = *reinterpret_cast<const f4*>(&myrow[((k ^ jx) << 2)]);
#pragma unroll
                for (int m = 0; m < 4; ++m) {
                    const int tl = k * 4 + m;
                    float x = x4[m];
                    // reference association: v = v + ((-v/20) + x)
                    float d  = x - div20(v);
                    float vn = v + d;
                    bool fire = vn >= 1.0f;
                    numL = fire ? numL + tl : numL;
                    if (tl < 32)      b0 |= fire ? (1u << tl) : 0u;
                    else if (tl < 64) b1 |= fire ? (1u << (tl - 32)) : 0u;
                    else              b2 |= fire ? (1u << (tl - 64)) : 0u;
                    v = fire ? 0.0f : vn;
                }
            }
            int cntC = __builtin_popcount(b0) + __builtin_popcount(b1) +
                       __builtin_popcount(b2);
            int fl = b0 ? __builtin_ctz(b0)
                   : (b1 ? 32 + __builtin_ctz(b1)
                   : (b2 ? 64 + __builtin_ctz(b2) : -1));
            int cbase = c * TC;
            num += numL + cbase * cntC;
            cnt += cntC;
            first = min(first, fl >= 0 ? cbase + fl : BIG);

            bitsb[j * 3 + 0] = b0;
            bitsb[j * 3 + 1] = b1;
            bitsb[j * 3 + 2] = b2;
        }
        // single wave: exec reconverges; DS in-order -> expand sees bits

        // ---- expand: all 64 lanes, coalesced full-line nt stores ----
        {
            int r = r0, k = k0;
            int off = r * 1600 + k * 16 + c * 320;
#pragma unroll
            for (int i = 0; i < F4T; ++i) {
                unsigned w = bitsb[r * 3 + (k >> 3)];
                int sh = (k & 7) * 4;
                f4 s;
                s.x = (float)((w >> (sh + 0)) & 1u);
                s.y = (float)((w >> (sh + 1)) & 1u);
                s.z = (float)((w >> (sh + 2)) & 1u);
                s.w = (float)((w >> (sh + 3)) & 1u);
                __builtin_nontemporal_store(s, reinterpret_cast<f4*>(Sb + off));
                int kn = k + 4; bool cr = kn >= 20;
                k = cr ? kn - 20 : kn;
                r += cr ? 4 : 3;
                off += cr ? 6144 : 4864;
            }
        }

        if (c + 1 < NC) write_lds(regs);
    }

    if (j < ROWS) {
        const int row = R0 + j;
        hard_lat[row] = (float)(first == BIG ? 0 : first);
        soft_lat[row] = (float)num / ((float)cnt + 1e-6f);
    }
}

extern "C" void kernel_launch(void* const* d_in, const int* in_sizes, int n_in,
                              void* d_out, int out_size, void* d_ws, size_t ws_size,
                              hipStream_t stream) {
    const float* I = (const float*)d_in[0];
    int B = in_sizes[0] / L_LEN;  // 65536

    float* spk = (float*)d_out;
    float* hard = spk + (size_t)B * L_LEN;
    float* soft = hard + B;

    dim3 block(64);
    dim3 grid(B / ROWS);  // 2048 blocks -> 8 blocks/CU = 2 waves/SIMD
    hipLaunchKernelGGL(lif_kernel, grid, block, 0, stream, I, spk, hard, soft);
}